// Round 7
// baseline (1004.826 us; speedup 1.0000x reference)
//
#include <hip/hip_runtime.h>
#include <hip/hip_bf16.h>

#define GEN_EPS 1e-7f

typedef __attribute__((ext_vector_type(8))) short short8;
typedef __attribute__((ext_vector_type(4))) float f32x4;

// ---------------------------------------------------------------------------
// h = relu(LayerNorm(x)) stored as bf16.  One wave per row (C=128, 2 ch/lane).
// ---------------------------------------------------------------------------
__global__ void ln_relu_kernel(const float* __restrict__ x, const float* __restrict__ g,
                               const float* __restrict__ b, __hip_bfloat16* __restrict__ h,
                               int M) {
  int lane = threadIdx.x & 63;
  int r = blockIdx.x * 4 + (threadIdx.x >> 6);
  if (r >= M) return;
  float2 v = ((const float2*)(x + (size_t)r * 128))[lane];
  float s = v.x + v.y;
#pragma unroll
  for (int o = 32; o; o >>= 1) s += __shfl_xor(s, o);
  float m = s * (1.0f / 128.0f);
  float dx = v.x - m, dy = v.y - m;
  float q = dx * dx + dy * dy;
#pragma unroll
  for (int o = 32; o; o >>= 1) q += __shfl_xor(q, o);
  float rstd = rsqrtf(q * (1.0f / 128.0f) + 1e-5f);
  float2 gv = ((const float2*)g)[lane], bv = ((const float2*)b)[lane];
  float2 hv;
  hv.x = fmaxf(fmaf(dx * rstd, gv.x, bv.x), 0.0f);
  hv.y = fmaxf(fmaf(dy * rstd, gv.y, bv.y), 0.0f);
  ((__hip_bfloat162*)(h + (size_t)r * 128))[lane] = __float22bfloat162_rn(hv);
}

// ---------------------------------------------------------------------------
// Weight pack into MFMA-fragment order:
//   WP[(c>>4)*(16*R) + (k>>5)*512 + (c&15)*32 + (k&31)] = bf16(W[k][c])
// ---------------------------------------------------------------------------
__global__ void wprep_kernel(const float* __restrict__ W, short* __restrict__ WP,
                             int R, int Cc) {
  int c = blockIdx.x;
  size_t tbase = (size_t)(c >> 4) * (size_t)(16 * R);
  int rsub = c & 15;
  for (int k = threadIdx.x; k < R; k += blockDim.x) {
    __hip_bfloat16 bv = __float2bfloat16(W[(size_t)k * Cc + c]);
    WP[tbase + (size_t)(k >> 5) * 512 + rsub * 32 + (k & 31)] = *(short*)&bv;
  }
}

// ---------------------------------------------------------------------------
// CSR construction: count -> scan -> fill
// ---------------------------------------------------------------------------
__global__ void count_kernel(const int* __restrict__ dst, int* __restrict__ counts, int nnz) {
  int i = blockIdx.x * blockDim.x + threadIdx.x;
  if (i < nnz) atomicAdd(&counts[dst[i]], 1);
}

__global__ void scan_block_sums(const int* __restrict__ counts, int* __restrict__ bsums, int M) {
  __shared__ int sm[256];
  int t = threadIdx.x;
  int base = blockIdx.x * 1024 + t * 4;
  int s = 0;
#pragma unroll
  for (int i = 0; i < 4; i++) {
    int idx = base + i;
    if (idx < M) s += counts[idx];
  }
  sm[t] = s;
  __syncthreads();
  for (int o = 128; o; o >>= 1) {
    if (t < o) sm[t] += sm[t + o];
    __syncthreads();
  }
  if (t == 0) bsums[blockIdx.x] = sm[0];
}

// one-block exclusive scan over up to 512 block sums
__global__ void scan_bsums(int* bsums, int nb) {
  __shared__ int sm[512];
  int t = threadIdx.x;
  int v = (t < nb) ? bsums[t] : 0;
  sm[t] = v;
  __syncthreads();
  for (int o = 1; o < 512; o <<= 1) {
    int u = (t >= o) ? sm[t - o] : 0;
    __syncthreads();
    sm[t] += u;
    __syncthreads();
  }
  if (t < nb) bsums[t] = sm[t] - v;  // exclusive
}

__global__ void scan_write(const int* __restrict__ counts, const int* __restrict__ bsums,
                           int* __restrict__ off, int* __restrict__ cursor, int M, int nnz) {
  __shared__ int sm[256];
  int t = threadIdx.x;
  int base = blockIdx.x * 1024 + t * 4;
  int c[4];
  int s = 0;
#pragma unroll
  for (int i = 0; i < 4; i++) {
    int idx = base + i;
    c[i] = (idx < M) ? counts[idx] : 0;
    s += c[i];
  }
  sm[t] = s;
  __syncthreads();
  for (int o = 1; o < 256; o <<= 1) {
    int v = (t >= o) ? sm[t - o] : 0;
    __syncthreads();
    sm[t] += v;
    __syncthreads();
  }
  int p = bsums[blockIdx.x] + sm[t] - s;
#pragma unroll
  for (int i = 0; i < 4; i++) {
    int idx = base + i;
    if (idx < M) {
      off[idx] = p;
      cursor[idx] = p;
      p += c[i];
    }
  }
  if (blockIdx.x == 0 && t == 0) off[M] = nnz;
}

template <bool HAS_EID>
__global__ void fill_kernel(const int* __restrict__ src, const int* __restrict__ dst,
                            int* __restrict__ cursor, int* __restrict__ csr_src,
                            int* __restrict__ csr_eid, int nnz) {
  int i = blockIdx.x * blockDim.x + threadIdx.x;
  if (i >= nnz) return;
  int d = dst[i];
  int p = atomicAdd(&cursor[d], 1);
  csr_src[p] = src[i];
  if (HAS_EID) csr_eid[p] = i;
}

// ---------------------------------------------------------------------------
// Softmax aggregation, one wave per destination row, 2 channels per lane.
// eattr (when present) is read as bf16 (row-major [*,128]).
// Writes y bf16 PRE-PACKED in MFMA fragment order.
// ---------------------------------------------------------------------------
template <bool HAS_EATTR>
__global__ __launch_bounds__(256) void aggregate_kernel(
    const __hip_bfloat16* __restrict__ h, const int* __restrict__ off,
    const int* __restrict__ csr_src, const int* __restrict__ csr_eid,
    const ushort* __restrict__ eattr, const float* __restrict__ tptr,
    uint* __restrict__ yP, int M) {
  int lane = threadIdx.x & 63;
  int r = blockIdx.x * 4 + (threadIdx.x >> 6);
  if (r >= M) return;
  const float t = tptr[0];
  float2 hv = __bfloat1622float2(((const __hip_bfloat162*)(h + (size_t)r * 128))[lane]);
  int e0 = off[r], e1 = off[r + 1];
  float d0 = 0.0f, d1 = 0.0f, a0 = 0.0f, a1 = 0.0f;
  int sN = 0, idN = 0;
  if (e0 < e1) {
    sN = csr_src[e0];
    if (HAS_EATTR) idN = csr_eid[e0];
  }
  for (int e = e0; e < e1; e++) {
    int s = sN, id = idN;
    if (e + 1 < e1) {
      sN = csr_src[e + 1];
      if (HAS_EATTR) idN = csr_eid[e + 1];
    }
    float2 mv = __bfloat1622float2(((const __hip_bfloat162*)(h + (size_t)s * 128))[lane]);
    if (HAS_EATTR) {
      uint ea = ((const uint*)(eattr + (size_t)id * 128))[lane];
      float2 ef = __bfloat1622float2(*(__hip_bfloat162*)&ea);
      mv.x += ef.x;
      mv.y += ef.y;
    }
    float m0 = fmaxf(mv.x, 0.0f) + GEN_EPS;
    float m1 = fmaxf(mv.y, 0.0f) + GEN_EPS;
    float al0 = __expf(m0 * t), al1 = __expf(m1 * t);
    d0 += al0;
    d1 += al1;
    a0 = fmaf(al0, m0, a0);
    a1 = fmaf(al1, m1, a1);
  }
  float2 yv;
  yv.x = (e1 > e0 ? a0 / d0 : 0.0f) + hv.x;
  yv.y = (e1 > e0 ? a1 / d1 : 0.0f) + hv.y;
  __hip_bfloat162 yb2 = __float22bfloat162_rn(yv);
  yP[(r >> 4) * 1024 + (lane >> 4) * 256 + (r & 15) * 16 + (lane & 15)] = *(uint*)&yb2;
}

// ---------------------------------------------------------------------------
// MLP: fully wave-independent.  Each wave owns a 16-row tile end-to-end:
//   GEMM1 16x256 (C1=16 frags) -> +b1 -> in-wave LN (shfl over 16-lane group)
//   -> relu -> wave-private LDS H slice -> GEMM2 16x128 -> out = C2 + b2 + x.
// No __syncthreads anywhere.  Grid-stride loop: next tile's y prefetched
// during GEMM1; x issued after H-write (hidden under GEMM2).
// If WRITE_BF16, also emits bf16 out copy (aliases yP: each tile region is
// read (yA) strictly before being overwritten, only by its owner wave).
// ---------------------------------------------------------------------------
template <bool WRITE_BF16>
__global__ __launch_bounds__(256, 2) void mlp_kernel(
    const float* __restrict__ x, const short* yP, const short* __restrict__ W1P,
    const float* __restrict__ b1, const float* __restrict__ lng,
    const float* __restrict__ lnb, const short* __restrict__ W2P,
    const float* __restrict__ b2, float* __restrict__ out, ushort* out16,
    int ntiles, int stride, int M) {
  __shared__ short HsAll[4][16 * 268];
  const int lane = threadIdx.x & 63, wv = threadIdx.x >> 6;
  short* Hs = HsAll[wv];
  const int rA = lane & 15, hi = lane >> 4;
  const int kA = hi * 8, jrow = hi * 4;
  const int fo = rA * 32 + kA;

  // loop-invariant per-lane params
  float b1v[16], lngv[16], lnbv[16], b2v[8];
#pragma unroll
  for (int ct = 0; ct < 16; ct++) {
    int col = ct * 16 + rA;
    b1v[ct] = b1[col];
    lngv[ct] = lng[col];
    lnbv[ct] = lnb[col];
  }
#pragma unroll
  for (int ct = 0; ct < 8; ct++) b2v[ct] = b2[ct * 16 + rA];

  int t = blockIdx.x * 4 + wv;
  short8 yA0, yA1, yA2, yA3;
  if (t < ntiles) {
    const short* yb = yP + (size_t)t * 2048 + fo;
    yA0 = *(const short8*)(yb);
    yA1 = *(const short8*)(yb + 512);
    yA2 = *(const short8*)(yb + 1024);
    yA3 = *(const short8*)(yb + 1536);
  }

  for (; t < ntiles; t += stride) {
    const int row0 = t * 16;

    // ---- GEMM1: 16 rows x 256 cols ----
    f32x4 C1[16];
#pragma unroll
    for (int i = 0; i < 16; i++) C1[i] = (f32x4)0.0f;
#pragma unroll
    for (int kc = 0; kc < 4; kc++) {
      short8 a = (kc == 0) ? yA0 : (kc == 1) ? yA1 : (kc == 2) ? yA2 : yA3;
#pragma unroll
      for (int ct = 0; ct < 16; ct++) {
        short8 B = *(const short8*)&W1P[(size_t)ct * 2048 + kc * 512 + fo];
        C1[ct] = __builtin_amdgcn_mfma_f32_16x16x32_bf16(a, B, C1[ct], 0, 0, 0);
      }
    }

    // ---- prefetch next tile's y (hidden under LN + GEMM2) ----
    {
      int tn = t + stride;
      int tc = (tn < ntiles) ? tn : t;  // clamp: harmless reload on last iter
      const short* yb = yP + (size_t)tc * 2048 + fo;
      yA0 = *(const short8*)(yb);
      yA1 = *(const short8*)(yb + 512);
      yA2 = *(const short8*)(yb + 1024);
      yA3 = *(const short8*)(yb + 1536);
    }

    // ---- +b1, in-wave LN stats (16-lane shfl butterfly) ----
#pragma unroll
    for (int ct = 0; ct < 16; ct++)
#pragma unroll
      for (int j = 0; j < 4; j++) C1[ct][j] += b1v[ct];

    float mean[4], rstd[4];
#pragma unroll
    for (int j = 0; j < 4; j++) {
      float p = 0.0f, q = 0.0f;
#pragma unroll
      for (int ct = 0; ct < 16; ct++) {
        p += C1[ct][j];
        q = fmaf(C1[ct][j], C1[ct][j], q);
      }
#pragma unroll
      for (int o = 1; o < 16; o <<= 1) {
        p += __shfl_xor(p, o);
        q += __shfl_xor(q, o);
      }
      float m = p * (1.0f / 256.0f);
      mean[j] = m;
      rstd[j] = rsqrtf(q * (1.0f / 256.0f) - m * m + 1e-5f);
    }

    // ---- normalize + relu -> wave-private Hs ----
#pragma unroll
    for (int ct = 0; ct < 16; ct++) {
#pragma unroll
      for (int j = 0; j < 4; j++) {
        float v = fmaxf(fmaf((C1[ct][j] - mean[j]) * rstd[j], lngv[ct], lnbv[ct]), 0.0f);
        __hip_bfloat16 bv = __float2bfloat16(v);
        Hs[(jrow + j) * 268 + ct * 16 + rA] = *(short*)&bv;
      }
    }

    // ---- x residual issue (hidden under GEMM2; C1 dead -> regs free) ----
    float xv[32];
#pragma unroll
    for (int ct = 0; ct < 8; ct++)
#pragma unroll
      for (int j = 0; j < 4; j++) {
        int row = row0 + jrow + j;
        int rr = (row < M) ? row : (M - 1);
        xv[ct * 4 + j] = x[(size_t)rr * 128 + ct * 16 + rA];
      }

    // LDS write->read fence (same wave, cross-lane): rule #18
    asm volatile("s_waitcnt lgkmcnt(0)" ::: "memory");
    __builtin_amdgcn_sched_barrier(0);

    // ---- GEMM2: 16 rows x 128 cols ----
    f32x4 C2[8];
#pragma unroll
    for (int i = 0; i < 8; i++) C2[i] = (f32x4)0.0f;
#pragma unroll
    for (int kc = 0; kc < 8; kc++) {
      short8 a = *(const short8*)&Hs[rA * 268 + kc * 32 + kA];
#pragma unroll
      for (int ct = 0; ct < 8; ct++) {
        short8 B = *(const short8*)&W2P[(size_t)ct * 4096 + kc * 512 + fo];
        C2[ct] = __builtin_amdgcn_mfma_f32_16x16x32_bf16(a, B, C2[ct], 0, 0, 0);
      }
    }

    // ---- epilogue: out = C2 + b2 + x (+ optional bf16 copy) ----
#pragma unroll
    for (int ct = 0; ct < 8; ct++) {
#pragma unroll
      for (int j = 0; j < 4; j++) {
        int row = row0 + jrow + j;
        if (row < M) {
          size_t idx = (size_t)row * 128 + ct * 16 + rA;
          float o = C2[ct][j] + b2v[ct] + xv[ct * 4 + j];
          out[idx] = o;
          if (WRITE_BF16) {
            __hip_bfloat16 bo = __float2bfloat16(o);
            out16[idx] = *(ushort*)&bo;
          }
        }
      }
    }
  }
}

// ---------------------------------------------------------------------------
extern "C" void kernel_launch(void* const* d_in, const int* in_sizes, int n_in,
                              void* d_out, int out_size, void* d_ws, size_t ws_size,
                              hipStream_t stream) {
  const int C = 128;
  const float* v_x = (const float*)d_in[0];
  const float* e_x = (const float*)d_in[1];
  const int* v_ei = (const int*)d_in[2];
  const int* e_ei = (const int*)d_in[3];
  const int N = in_sizes[0] / C;
  const int E = in_sizes[1] / C;
  const int LE = in_sizes[3] / 2;

  const float* ep[9];
  const float* np_[9];
  for (int i = 0; i < 9; i++) ep[i] = (const float*)d_in[4 + i];
  for (int i = 0; i < 9; i++) np_[i] = (const float*)d_in[13 + i];

  float* v_out = (float*)d_out;
  float* e_out = (float*)d_out + (size_t)N * C;

  char* wsp = (char*)d_ws;
  size_t o = 0;
  auto carve = [&](size_t bytes) {
    void* p = wsp + o;
    o += (bytes + 255) & ~(size_t)255;
    return p;
  };
  short* yPe = (short*)carve((size_t)E * C * 2);  // edge packed y; later bf16 e_out
  short* yPn = (short*)carve((size_t)N * C * 2);  // node packed y
  int* counts = (int*)carve((size_t)E * 4);
  int* off = (int*)carve(((size_t)E + 1) * 4);
  int* cursor = (int*)carve((size_t)E * 4);
  int* bsums = (int*)carve(4096);
  int* csr_src = (int*)carve((size_t)LE * 4);
  int* csr_eid = (int*)carve((size_t)LE * 4);
  short* eW1P = (short*)carve((size_t)256 * 128 * 2);
  short* eW2P = (short*)carve((size_t)128 * 256 * 2);
  short* nW1P = (short*)carve((size_t)256 * 128 * 2);
  short* nW2P = (short*)carve((size_t)128 * 256 * 2);
  (void)ws_size;
  (void)n_in;
  (void)out_size;

  // h lives in the (fp32-sized) output region as bf16; dead before mlp writes.
  auto run_layer = [&](const float* x, const int* ei, int M, int nnz,
                       const ushort* eattr, const float** P, short* W1P, short* W2P,
                       short* yP, float* outp, ushort* out16) {
    const int* src = ei;
    const int* dst = ei + nnz;
    __hip_bfloat16* h = (__hip_bfloat16*)outp;
    hipMemsetAsync(counts, 0, (size_t)M * 4, stream);
    wprep_kernel<<<256, 128, 0, stream>>>(P[3], W1P, 128, 256);
    wprep_kernel<<<128, 256, 0, stream>>>(P[7], W2P, 256, 128);
    ln_relu_kernel<<<(M + 3) / 4, 256, 0, stream>>>(x, P[0], P[1], h, M);
    count_kernel<<<(nnz + 255) / 256, 256, 0, stream>>>(dst, counts, nnz);
    int nb = (M + 1023) / 1024;
    scan_block_sums<<<nb, 256, 0, stream>>>(counts, bsums, M);
    scan_bsums<<<1, 512, 0, stream>>>(bsums, nb);
    scan_write<<<nb, 256, 0, stream>>>(counts, bsums, off, cursor, M, nnz);
    if (eattr) {
      fill_kernel<true><<<(nnz + 255) / 256, 256, 0, stream>>>(src, dst, cursor, csr_src,
                                                               csr_eid, nnz);
      aggregate_kernel<true><<<(M + 3) / 4, 256, 0, stream>>>(h, off, csr_src, csr_eid,
                                                              eattr, P[2], (uint*)yP, M);
    } else {
      fill_kernel<false><<<(nnz + 255) / 256, 256, 0, stream>>>(src, dst, cursor, csr_src,
                                                                csr_eid, nnz);
      aggregate_kernel<false><<<(M + 3) / 4, 256, 0, stream>>>(h, off, csr_src, csr_eid,
                                                               nullptr, P[2], (uint*)yP, M);
    }
    int ntiles = (M + 15) / 16;
    int gblocks = (ntiles + 3) / 4;
    if (gblocks > 1024) gblocks = 1024;
    int stride = gblocks * 4;
    if (out16) {
      mlp_kernel<true><<<gblocks, 256, 0, stream>>>(x, yP, W1P, P[4], P[5], P[6], W2P,
                                                    P[8], outp, out16, ntiles, stride, M);
    } else {
      mlp_kernel<false><<<gblocks, 256, 0, stream>>>(x, yP, W1P, P[4], P[5], P[6], W2P,
                                                     P[8], outp, nullptr, ntiles, stride, M);
    }
  };

  // edge layer: also emit bf16 e_out copy into yPe (aliased, safe per-tile)
  run_layer(e_x, e_ei, E, LE, nullptr, ep, eW1P, eW2P, yPe, e_out, (ushort*)yPe);
  // node layer: eattr = bf16 e_out copy
  run_layer(v_x, v_ei, N, E, (const ushort*)yPe, np_, nW1P, nW2P, yPn, v_out, nullptr);
}

// Round 8
// 466.149 us; speedup vs baseline: 2.1556x; 2.1556x over previous
//
#include <hip/hip_runtime.h>
#include <hip/hip_bf16.h>

#define GEN_EPS 1e-7f

typedef __attribute__((ext_vector_type(8))) short short8;
typedef __attribute__((ext_vector_type(4))) float f32x4;

// ---------------------------------------------------------------------------
// h = relu(LayerNorm(x)) stored as bf16.  One wave per row (C=128, 2 ch/lane).
// ---------------------------------------------------------------------------
__global__ void ln_relu_kernel(const float* __restrict__ x, const float* __restrict__ g,
                               const float* __restrict__ b, __hip_bfloat16* __restrict__ h,
                               int M) {
  int lane = threadIdx.x & 63;
  int r = blockIdx.x * 4 + (threadIdx.x >> 6);
  if (r >= M) return;
  float2 v = ((const float2*)(x + (size_t)r * 128))[lane];
  float s = v.x + v.y;
#pragma unroll
  for (int o = 32; o; o >>= 1) s += __shfl_xor(s, o);
  float m = s * (1.0f / 128.0f);
  float dx = v.x - m, dy = v.y - m;
  float q = dx * dx + dy * dy;
#pragma unroll
  for (int o = 32; o; o >>= 1) q += __shfl_xor(q, o);
  float rstd = rsqrtf(q * (1.0f / 128.0f) + 1e-5f);
  float2 gv = ((const float2*)g)[lane], bv = ((const float2*)b)[lane];
  float2 hv;
  hv.x = fmaxf(fmaf(dx * rstd, gv.x, bv.x), 0.0f);
  hv.y = fmaxf(fmaf(dy * rstd, gv.y, bv.y), 0.0f);
  ((__hip_bfloat162*)(h + (size_t)r * 128))[lane] = __float22bfloat162_rn(hv);
}

// ---------------------------------------------------------------------------
// Weight pack into MFMA-fragment order:
//   WP[(c>>4)*(16*R) + (k>>5)*512 + (c&15)*32 + (k&31)] = bf16(W[k][c])
// ---------------------------------------------------------------------------
__global__ void wprep_kernel(const float* __restrict__ W, short* __restrict__ WP,
                             int R, int Cc) {
  int c = blockIdx.x;
  size_t tbase = (size_t)(c >> 4) * (size_t)(16 * R);
  int rsub = c & 15;
  for (int k = threadIdx.x; k < R; k += blockDim.x) {
    __hip_bfloat16 bv = __float2bfloat16(W[(size_t)k * Cc + c]);
    WP[tbase + (size_t)(k >> 5) * 512 + rsub * 32 + (k & 31)] = *(short*)&bv;
  }
}

// ---------------------------------------------------------------------------
// CSR construction: count -> scan -> fill
// ---------------------------------------------------------------------------
__global__ void count_kernel(const int* __restrict__ dst, int* __restrict__ counts, int nnz) {
  int i = blockIdx.x * blockDim.x + threadIdx.x;
  if (i < nnz) atomicAdd(&counts[dst[i]], 1);
}

__global__ void scan_block_sums(const int* __restrict__ counts, int* __restrict__ bsums, int M) {
  __shared__ int sm[256];
  int t = threadIdx.x;
  int base = blockIdx.x * 1024 + t * 4;
  int s = 0;
#pragma unroll
  for (int i = 0; i < 4; i++) {
    int idx = base + i;
    if (idx < M) s += counts[idx];
  }
  sm[t] = s;
  __syncthreads();
  for (int o = 128; o; o >>= 1) {
    if (t < o) sm[t] += sm[t + o];
    __syncthreads();
  }
  if (t == 0) bsums[blockIdx.x] = sm[0];
}

// one-block exclusive scan over up to 512 block sums
__global__ void scan_bsums(int* bsums, int nb) {
  __shared__ int sm[512];
  int t = threadIdx.x;
  int v = (t < nb) ? bsums[t] : 0;
  sm[t] = v;
  __syncthreads();
  for (int o = 1; o < 512; o <<= 1) {
    int u = (t >= o) ? sm[t - o] : 0;
    __syncthreads();
    sm[t] += u;
    __syncthreads();
  }
  if (t < nb) bsums[t] = sm[t] - v;  // exclusive
}

__global__ void scan_write(const int* __restrict__ counts, const int* __restrict__ bsums,
                           int* __restrict__ off, int* __restrict__ cursor, int M, int nnz) {
  __shared__ int sm[256];
  int t = threadIdx.x;
  int base = blockIdx.x * 1024 + t * 4;
  int c[4];
  int s = 0;
#pragma unroll
  for (int i = 0; i < 4; i++) {
    int idx = base + i;
    c[i] = (idx < M) ? counts[idx] : 0;
    s += c[i];
  }
  sm[t] = s;
  __syncthreads();
  for (int o = 1; o < 256; o <<= 1) {
    int v = (t >= o) ? sm[t - o] : 0;
    __syncthreads();
    sm[t] += v;
    __syncthreads();
  }
  int p = bsums[blockIdx.x] + sm[t] - s;
#pragma unroll
  for (int i = 0; i < 4; i++) {
    int idx = base + i;
    if (idx < M) {
      off[idx] = p;
      cursor[idx] = p;
      p += c[i];
    }
  }
  if (blockIdx.x == 0 && t == 0) off[M] = nnz;
}

template <bool HAS_EID>
__global__ void fill_kernel(const int* __restrict__ src, const int* __restrict__ dst,
                            int* __restrict__ cursor, int* __restrict__ csr_src,
                            int* __restrict__ csr_eid, int nnz) {
  int i = blockIdx.x * blockDim.x + threadIdx.x;
  if (i >= nnz) return;
  int d = dst[i];
  int p = atomicAdd(&cursor[d], 1);
  csr_src[p] = src[i];
  if (HAS_EID) csr_eid[p] = i;
}

// ---------------------------------------------------------------------------
// Softmax aggregation, one wave per destination row, 2 channels per lane.
// eattr (when present) is read as bf16 (row-major [*,128]).
// Writes y bf16 PRE-PACKED in MFMA fragment order.
// ---------------------------------------------------------------------------
template <bool HAS_EATTR>
__global__ __launch_bounds__(256) void aggregate_kernel(
    const __hip_bfloat16* __restrict__ h, const int* __restrict__ off,
    const int* __restrict__ csr_src, const int* __restrict__ csr_eid,
    const ushort* __restrict__ eattr, const float* __restrict__ tptr,
    uint* __restrict__ yP, int M) {
  int lane = threadIdx.x & 63;
  int r = blockIdx.x * 4 + (threadIdx.x >> 6);
  if (r >= M) return;
  const float t = tptr[0];
  float2 hv = __bfloat1622float2(((const __hip_bfloat162*)(h + (size_t)r * 128))[lane]);
  int e0 = off[r], e1 = off[r + 1];
  float d0 = 0.0f, d1 = 0.0f, a0 = 0.0f, a1 = 0.0f;
  int sN = 0, idN = 0;
  if (e0 < e1) {
    sN = csr_src[e0];
    if (HAS_EATTR) idN = csr_eid[e0];
  }
  for (int e = e0; e < e1; e++) {
    int s = sN, id = idN;
    if (e + 1 < e1) {
      sN = csr_src[e + 1];
      if (HAS_EATTR) idN = csr_eid[e + 1];
    }
    float2 mv = __bfloat1622float2(((const __hip_bfloat162*)(h + (size_t)s * 128))[lane]);
    if (HAS_EATTR) {
      uint ea = ((const uint*)(eattr + (size_t)id * 128))[lane];
      float2 ef = __bfloat1622float2(*(__hip_bfloat162*)&ea);
      mv.x += ef.x;
      mv.y += ef.y;
    }
    float m0 = fmaxf(mv.x, 0.0f) + GEN_EPS;
    float m1 = fmaxf(mv.y, 0.0f) + GEN_EPS;
    float al0 = __expf(m0 * t), al1 = __expf(m1 * t);
    d0 += al0;
    d1 += al1;
    a0 = fmaf(al0, m0, a0);
    a1 = fmaf(al1, m1, a1);
  }
  float2 yv;
  yv.x = (e1 > e0 ? a0 / d0 : 0.0f) + hv.x;
  yv.y = (e1 > e0 ? a1 / d1 : 0.0f) + hv.y;
  __hip_bfloat162 yb2 = __float22bfloat162_rn(yv);
  yP[(r >> 4) * 1024 + (lane >> 4) * 256 + (r & 15) * 16 + (lane & 15)] = *(uint*)&yb2;
}

// ---------------------------------------------------------------------------
// Persistent MLP: 256 blocks x 512 threads (8 waves).  Block stages packed
// W1+W2 (128 KB) into LDS ONCE, then each wave independently grid-strides
// over 16-row tiles (no barriers in the loop):
//   GEMM1 16x256 (B-frags ds_read from LDS) -> +b1 -> in-wave LN (shfl)
//   -> kc-fused GEMM2: per 32 hidden cols: normalize+relu -> per-wave LDS
//      scratch (double-buffered) -> A-frag ds_read -> 8 MFMA.
//   -> out = C2 + b2 + x (+ optional bf16 copy aliasing yP, safe per-tile).
// ---------------------------------------------------------------------------
template <bool WRITE_BF16>
__global__ __launch_bounds__(512, 2) void mlp_kernel(
    const float* __restrict__ x, const short* yP, const short* __restrict__ W1P,
    const float* __restrict__ b1, const float* __restrict__ lng,
    const float* __restrict__ lnb, const short* __restrict__ W2P,
    const float* __restrict__ b2, float* __restrict__ out, ushort* out16,
    int ntiles, int stride, int M) {
  __shared__ short W1s[128 * 256];      // 64 KB, packed frag order
  __shared__ short W2s[256 * 128];      // 64 KB, packed frag order
  __shared__ short scr[8][2][16 * 34];  // per-wave double-buffered H scratch

  const int tid = threadIdx.x, lane = tid & 63, wv = tid >> 6;
  const int rA = lane & 15, hi = lane >> 4;
  const int kA = hi * 8, jrow = hi * 4;
  const int fo = rA * 32 + kA;

  // ---- stage W1/W2 -> LDS (once; reg-staged, coalesced) ----
  {
    const short8* g1 = (const short8*)W1P;
    short8* l1 = (short8*)W1s;
#pragma unroll
    for (int i = 0; i < 8; i++) l1[i * 512 + tid] = g1[i * 512 + tid];
    const short8* g2 = (const short8*)W2P;
    short8* l2 = (short8*)W2s;
#pragma unroll
    for (int i = 0; i < 8; i++) l2[i * 512 + tid] = g2[i * 512 + tid];
  }

  // loop-invariant per-lane params (overlap with staging)
  float b1v[16], lngv[16], lnbv[16], b2v[8];
#pragma unroll
  for (int ct = 0; ct < 16; ct++) {
    int col = ct * 16 + rA;
    b1v[ct] = b1[col];
    lngv[ct] = lng[col];
    lnbv[ct] = lnb[col];
  }
#pragma unroll
  for (int ct = 0; ct < 8; ct++) b2v[ct] = b2[ct * 16 + rA];

  __syncthreads();  // W resident; waves independent from here on

  int t = blockIdx.x * 8 + wv;
  short8 yA0, yA1, yA2, yA3;
  if (t < ntiles) {
    const short* yb = yP + (size_t)t * 2048 + fo;
    yA0 = *(const short8*)(yb);
    yA1 = *(const short8*)(yb + 512);
    yA2 = *(const short8*)(yb + 1024);
    yA3 = *(const short8*)(yb + 1536);
  }

  for (; t < ntiles; t += stride) {
    const int row0 = t * 16;

    // ---- GEMM1: 16 rows x 256 cols, B from LDS ----
    f32x4 C1[16];
#pragma unroll
    for (int i = 0; i < 16; i++) C1[i] = (f32x4)0.0f;
#pragma unroll
    for (int kc = 0; kc < 4; kc++) {
      short8 a = (kc == 0) ? yA0 : (kc == 1) ? yA1 : (kc == 2) ? yA2 : yA3;
#pragma unroll
      for (int ct = 0; ct < 16; ct++) {
        short8 B = *(const short8*)&W1s[ct * 2048 + kc * 512 + fo];
        C1[ct] = __builtin_amdgcn_mfma_f32_16x16x32_bf16(a, B, C1[ct], 0, 0, 0);
      }
    }

    // ---- prefetch next tile's y (hidden under LN + GEMM2) ----
    {
      int tn = t + stride;
      int tc = (tn < ntiles) ? tn : t;
      const short* yb = yP + (size_t)tc * 2048 + fo;
      yA0 = *(const short8*)(yb);
      yA1 = *(const short8*)(yb + 512);
      yA2 = *(const short8*)(yb + 1024);
      yA3 = *(const short8*)(yb + 1536);
    }

    // ---- x residual issue early (hidden under LN + GEMM2) ----
    float xv[32];
#pragma unroll
    for (int ct = 0; ct < 8; ct++)
#pragma unroll
      for (int j = 0; j < 4; j++) {
        int row = row0 + jrow + j;
        int rr = (row < M) ? row : (M - 1);
        xv[ct * 4 + j] = x[(size_t)rr * 128 + ct * 16 + rA];
      }

    // ---- +b1, in-wave LN stats (16-lane shfl butterfly) ----
#pragma unroll
    for (int ct = 0; ct < 16; ct++)
#pragma unroll
      for (int j = 0; j < 4; j++) C1[ct][j] += b1v[ct];

    float mean[4], rstd[4];
#pragma unroll
    for (int j = 0; j < 4; j++) {
      float p = 0.0f, q = 0.0f;
#pragma unroll
      for (int ct = 0; ct < 16; ct++) {
        p += C1[ct][j];
        q = fmaf(C1[ct][j], C1[ct][j], q);
      }
#pragma unroll
      for (int o = 1; o < 16; o <<= 1) {
        p += __shfl_xor(p, o);
        q += __shfl_xor(q, o);
      }
      float m = p * (1.0f / 256.0f);
      mean[j] = m;
      rstd[j] = rsqrtf(q * (1.0f / 256.0f) - m * m + 1e-5f);
    }

    // ---- kc-fused: normalize 32 cols -> scratch -> A-frag -> 8 MFMA ----
    f32x4 C2[8];
#pragma unroll
    for (int i = 0; i < 8; i++) C2[i] = (f32x4)0.0f;
#pragma unroll
    for (int kc = 0; kc < 8; kc++) {
      short* s = &scr[wv][kc & 1][0];
#pragma unroll
      for (int ct2 = 0; ct2 < 2; ct2++) {
        int ctg = kc * 2 + ct2;
#pragma unroll
        for (int j = 0; j < 4; j++) {
          float v =
              fmaxf(fmaf((C1[ctg][j] - mean[j]) * rstd[j], lngv[ctg], lnbv[ctg]), 0.0f);
          __hip_bfloat16 bv = __float2bfloat16(v);
          s[(jrow + j) * 34 + ct2 * 16 + rA] = *(short*)&bv;
        }
      }
      // same-wave LDS write->cross-lane-read fence (rule #18)
      asm volatile("s_waitcnt lgkmcnt(0)" ::: "memory");
      __builtin_amdgcn_sched_barrier(0);
      short8 a = *(const short8*)&s[rA * 34 + kA];
#pragma unroll
      for (int ct = 0; ct < 8; ct++) {
        short8 B = *(const short8*)&W2s[ct * 4096 + kc * 512 + fo];
        C2[ct] = __builtin_amdgcn_mfma_f32_16x16x32_bf16(a, B, C2[ct], 0, 0, 0);
      }
    }

    // ---- epilogue: out = C2 + b2 + x (+ optional bf16 copy) ----
#pragma unroll
    for (int ct = 0; ct < 8; ct++) {
#pragma unroll
      for (int j = 0; j < 4; j++) {
        int row = row0 + jrow + j;
        if (row < M) {
          size_t idx = (size_t)row * 128 + ct * 16 + rA;
          float o = C2[ct][j] + b2v[ct] + xv[ct * 4 + j];
          out[idx] = o;
          if (WRITE_BF16) {
            __hip_bfloat16 bo = __float2bfloat16(o);
            out16[idx] = *(ushort*)&bo;
          }
        }
      }
    }
  }
}

// ---------------------------------------------------------------------------
extern "C" void kernel_launch(void* const* d_in, const int* in_sizes, int n_in,
                              void* d_out, int out_size, void* d_ws, size_t ws_size,
                              hipStream_t stream) {
  const int C = 128;
  const float* v_x = (const float*)d_in[0];
  const float* e_x = (const float*)d_in[1];
  const int* v_ei = (const int*)d_in[2];
  const int* e_ei = (const int*)d_in[3];
  const int N = in_sizes[0] / C;
  const int E = in_sizes[1] / C;
  const int LE = in_sizes[3] / 2;

  const float* ep[9];
  const float* np_[9];
  for (int i = 0; i < 9; i++) ep[i] = (const float*)d_in[4 + i];
  for (int i = 0; i < 9; i++) np_[i] = (const float*)d_in[13 + i];

  float* v_out = (float*)d_out;
  float* e_out = (float*)d_out + (size_t)N * C;

  char* wsp = (char*)d_ws;
  size_t o = 0;
  auto carve = [&](size_t bytes) {
    void* p = wsp + o;
    o += (bytes + 255) & ~(size_t)255;
    return p;
  };
  short* yPe = (short*)carve((size_t)E * C * 2);  // edge packed y; later bf16 e_out
  short* yPn = (short*)carve((size_t)N * C * 2);  // node packed y
  int* counts = (int*)carve((size_t)E * 4);
  int* off = (int*)carve(((size_t)E + 1) * 4);
  int* cursor = (int*)carve((size_t)E * 4);
  int* bsums = (int*)carve(4096);
  int* csr_src = (int*)carve((size_t)LE * 4);
  int* csr_eid = (int*)carve((size_t)LE * 4);
  short* eW1P = (short*)carve((size_t)256 * 128 * 2);
  short* eW2P = (short*)carve((size_t)128 * 256 * 2);
  short* nW1P = (short*)carve((size_t)256 * 128 * 2);
  short* nW2P = (short*)carve((size_t)128 * 256 * 2);
  (void)ws_size;
  (void)n_in;
  (void)out_size;

  // h lives in the (fp32-sized) output region as bf16; dead before mlp writes.
  auto run_layer = [&](const float* x, const int* ei, int M, int nnz,
                       const ushort* eattr, const float** P, short* W1P, short* W2P,
                       short* yP, float* outp, ushort* out16) {
    const int* src = ei;
    const int* dst = ei + nnz;
    __hip_bfloat16* h = (__hip_bfloat16*)outp;
    hipMemsetAsync(counts, 0, (size_t)M * 4, stream);
    wprep_kernel<<<256, 128, 0, stream>>>(P[3], W1P, 128, 256);
    wprep_kernel<<<128, 256, 0, stream>>>(P[7], W2P, 256, 128);
    ln_relu_kernel<<<(M + 3) / 4, 256, 0, stream>>>(x, P[0], P[1], h, M);
    count_kernel<<<(nnz + 255) / 256, 256, 0, stream>>>(dst, counts, nnz);
    int nb = (M + 1023) / 1024;
    scan_block_sums<<<nb, 256, 0, stream>>>(counts, bsums, M);
    scan_bsums<<<1, 512, 0, stream>>>(bsums, nb);
    scan_write<<<nb, 256, 0, stream>>>(counts, bsums, off, cursor, M, nnz);
    if (eattr) {
      fill_kernel<true><<<(nnz + 255) / 256, 256, 0, stream>>>(src, dst, cursor, csr_src,
                                                               csr_eid, nnz);
      aggregate_kernel<true><<<(M + 3) / 4, 256, 0, stream>>>(h, off, csr_src, csr_eid,
                                                              eattr, P[2], (uint*)yP, M);
    } else {
      fill_kernel<false><<<(nnz + 255) / 256, 256, 0, stream>>>(src, dst, cursor, csr_src,
                                                                csr_eid, nnz);
      aggregate_kernel<false><<<(M + 3) / 4, 256, 0, stream>>>(h, off, csr_src, csr_eid,
                                                               nullptr, P[2], (uint*)yP, M);
    }
    int ntiles = (M + 15) / 16;
    int gblocks = (ntiles + 7) / 8;
    if (gblocks > 256) gblocks = 256;
    int stride = gblocks * 8;
    if (out16) {
      mlp_kernel<true><<<gblocks, 512, 0, stream>>>(x, yP, W1P, P[4], P[5], P[6], W2P,
                                                    P[8], outp, out16, ntiles, stride, M);
    } else {
      mlp_kernel<false><<<gblocks, 512, 0, stream>>>(x, yP, W1P, P[4], P[5], P[6], W2P,
                                                     P[8], outp, nullptr, ntiles, stride, M);
    }
  };

  // edge layer: also emit bf16 e_out copy into yPe (aliased, safe per-tile)
  run_layer(e_x, e_ei, E, LE, nullptr, ep, eW1P, eW2P, yPe, e_out, (ushort*)yPe);
  // node layer: eattr = bf16 e_out copy
  run_layer(v_x, v_ei, N, E, (const ushort*)yPe, np_, nW1P, nW2P, yPn, v_out, nullptr);
}